// Round 15
// baseline (249.139 us; speedup 1.0000x reference)
//
#include <hip/hip_runtime.h>
#include <cfloat>

// Shapes (fixed by reference)
#define Bb 4
#define Tt 12
#define Nn 307
#define Wn 200        // windows: starts = 0,30,...,5970
#define ROW (Nn*64)   // 19648 floats per time-row
#define NT (Tt*Nn)    // 3684
#define KTOP 10
#define NUMEL 943104.0f  // B*64*N*T

// sims decomposition: window x sixth (a sixth = exactly 2 rows, 157KB contiguous)
#define NS 6
#define SIXTH (2*ROW)    // 39296 floats
#define SIXTH4 (SIXTH/4) // 9824 float4s

#define NG 77            // n-groups of 4 per t
#define NQW (Tt*NG)      // 924 producer blocks
#define GRID (Wn*NS)     // 1200
#define PROD_PER_SIXTH (2*NG)  // 154 producers signal each sixth

// workspace layout (float offsets)
#define WS_QWL  0                      // 235776: QWl[t][n][c] (flat == window layout)
#define WS_PART (WS_QWL + Tt*ROW)      // 1200  : part[s][w]
#define WS_RDY  (WS_PART + NS*Wn)      // 6 ints: per-sixth ready counters

// ---------- Kernel 1: fused qw + sims via producer->consumer flags ----------
// Blocks 0..923: compute qw slice (t=blk/77, 4 n's), release-signal ready[t/2].
// All blocks: bounded-spin (acquire) until their sixth's 154 producers done,
// then the proven flat-dot sims body. Producers hold the lowest block IDs and
// have no dependencies -> forward progress needs only >=924 resident blocks
// (have 1200 via 18.3KB LDS + launch_bounds(256,5)); spin is bounded (no hang).
__global__ __launch_bounds__(256, 5) void qws_kernel(
    const float* __restrict__ x, const float* __restrict__ hist,
    const float* __restrict__ Wq, const float* __restrict__ bq,
    const float* __restrict__ Wk, float* __restrict__ ws) {
    const int blk = blockIdx.x, tid = threadIdx.x;
    int* ready = (int*)(ws + WS_RDY);

    __shared__ float wqT[64*65];   // [cp*65+o] = Wq[o*64+cp] (pad 65: conflict-free stage)
    __shared__ float xsl[256], qb[256];
    __shared__ float red[4];

    if (blk < NQW) {               // ---- producer phase: qw ----
        int t = blk / NG, g = blk % NG;
        int n0 = g * 4;
        for (int i = tid; i < 4096; i += 256)
            wqT[(i & 63)*65 + (i >> 6)] = Wq[i];
        int w4 = tid >> 6, c = tid & 63;
        int n = n0 + w4;
        bool valid = (n < Nn);
        int ne = valid ? n : Nn - 1;
        size_t base = ((size_t)t * Nn + ne) * 64 + c;
        const size_t bs = (size_t)Tt * Nn * 64;
        float xs = x[base] + x[base + bs] + x[base + 2*bs] + x[base + 3*bs];
        xsl[w4*64 + c] = xs;
        __syncthreads();
        float q = 4.0f * bq[c];    // this thread computes o = c
        #pragma unroll 8
        for (int cp = 0; cp < 64; ++cp) q += wqT[cp*65 + c] * xsl[w4*64 + cp];
        qb[w4*64 + c] = q;
        __syncthreads();
        float q2 = 0.f;
        #pragma unroll 8
        for (int o = 0; o < 64; ++o) q2 += Wk[o*64 + c] * qb[w4*64 + o];  // L2-hot
        if (valid) ws[WS_QWL + (size_t)t * ROW + n*64 + c] = q2;
        __syncthreads();           // compiler drains vmem before barrier -> stores in L2
        if (tid == 0) {
            __threadfence();       // device-scope WB: QWl visible across XCDs
            __hip_atomic_fetch_add(&ready[t >> 1], 1, __ATOMIC_RELEASE,
                                   __HIP_MEMORY_SCOPE_AGENT);
        }
    }

    // ---- consumer phase: sims for (w, s) ----
    int w = blk / NS, s = blk % NS;
    if (tid == 0) {
        int spins = 0;
        while (__hip_atomic_load(&ready[s], __ATOMIC_ACQUIRE,
                                 __HIP_MEMORY_SCOPE_AGENT) < PROD_PER_SIXTH) {
            __builtin_amdgcn_s_sleep(2);
            if (++spins > (1 << 22)) break;   // anti-hang insurance; never hit when healthy
        }
        __threadfence();           // acquire side: invalidate L1/L2 -> fresh QWl
    }
    __syncthreads();

    const float4* a = (const float4*)(ws + WS_QWL + (size_t)s * SIXTH);
    const float4* b = (const float4*)(hist + (size_t)(30*w) * ROW + (size_t)s * SIXTH);
    float s0 = 0.f, s1 = 0.f;
    #pragma unroll 4
    for (int i = tid; i < SIXTH4; i += 256) {
        float4 av = a[i], bv = b[i];
        s0 += av.x*bv.x + av.y*bv.y;
        s1 += av.z*bv.z + av.w*bv.w;
    }
    float v = s0 + s1;
    #pragma unroll
    for (int off = 32; off > 0; off >>= 1) v += __shfl_down(v, off);
    int wave = tid >> 6;
    if ((tid & 63) == 0) red[wave] = v;
    __syncthreads();
    if (tid == 0)
        ws[WS_PART + s*Wn + w] = red[0] + red[1] + red[2] + red[3];
}

// ---------- Kernel 2: fused top-10 + softmax + aggregate + Wv/bv + broadcast ----------
// (R13 verbatim, proven) Every block recomputes top-k from part[] — identical
// fixed-order arithmetic -> deterministic; selection leaves identical tv/ti in
// all 64 lanes, softmax per-lane with no sync.
__global__ void agg_kernel(const float* __restrict__ hist, const float* __restrict__ Wv,
                           const float* __restrict__ bvv, const float* __restrict__ ws,
                           float* __restrict__ out) {
    int blk = blockIdx.x;            // t*N + n
    int t = blk / Nn, n = blk % Nn;
    int lane = threadIdx.x;          // 64 threads, one wave

    const float* part = ws + WS_PART;
    float v[4]; int ji[4];
    #pragma unroll
    for (int r = 0; r < 4; ++r) {
        int j = lane + 64*r;         // sims index 0..198; value = sims_all[j+1]
        ji[r] = (j < Wn - 1) ? j : (1 << 29);
        if (j < Wn - 1) {
            float sm = 0.f;
            #pragma unroll
            for (int ss = 0; ss < NS; ++ss) sm += part[ss*Wn + (j + 1)];
            v[r] = sm / NUMEL;
        } else v[r] = -FLT_MAX;
    }
    float tv[KTOP]; int ti[KTOP];
    for (int k = 0; k < KTOP; ++k) {
        float bv = -FLT_MAX; int bi = 1 << 29;
        #pragma unroll
        for (int r = 0; r < 4; ++r)
            if (v[r] > bv || (v[r] == bv && ji[r] < bi)) { bv = v[r]; bi = ji[r]; }
        #pragma unroll
        for (int off = 32; off > 0; off >>= 1) {
            float ov = __shfl_xor(bv, off);
            int   oi = __shfl_xor(bi, off);
            if (ov > bv || (ov == bv && oi < bi)) { bv = ov; bi = oi; }
        }
        tv[k] = bv; ti[k] = bi;      // identical in all lanes
        #pragma unroll
        for (int r = 0; r < 4; ++r) if (ji[r] == bi) v[r] = -FLT_MAX;
    }
    float corr[KTOP];
    {
        float m = tv[0], sum = 0.f;  // tv[0] is max (JAX order)
        #pragma unroll
        for (int k = 0; k < KTOP; ++k) { corr[k] = __expf(tv[k] - m); sum += corr[k]; }
        float inv = 1.0f / sum;
        #pragma unroll
        for (int k = 0; k < KTOP; ++k) corr[k] *= inv;
    }
    int c = lane;
    float a = 0.f;
    #pragma unroll
    for (int k = 0; k < KTOP; ++k) {
        int w = ti[k];               // windows[index], un-shifted (ref quirk)
        a += corr[k] * hist[(size_t)(30*w + t) * ROW + n*64 + c];
    }
    __shared__ float aw[64];
    aw[c] = a;
    __syncthreads();
    float acc = bvv[c];
    #pragma unroll 8
    for (int cc = 0; cc < 64; ++cc) acc += Wv[c*64 + cc] * aw[cc];
    #pragma unroll
    for (int b = 0; b < Bb; ++b)
        out[(((size_t)b*Tt + t)*Nn + n)*64 + c] = acc;
}

extern "C" void kernel_launch(void* const* d_in, const int* in_sizes, int n_in,
                              void* d_out, int out_size, void* d_ws, size_t ws_size,
                              hipStream_t stream) {
    const float* x    = (const float*)d_in[0];
    const float* hist = (const float*)d_in[1];
    const float* Wq   = (const float*)d_in[2];
    const float* bq   = (const float*)d_in[3];
    const float* Wk   = (const float*)d_in[4];
    // d_in[5] = bk: unused — uniform shift to all sims; top-k ordering and
    // softmax are shift-invariant, so the output is unaffected.
    const float* Wv   = (const float*)d_in[6];
    const float* bv   = (const float*)d_in[7];
    float* ws  = (float*)d_ws;
    float* out = (float*)d_out;

    // zero the 6 ready counters every call (ws poisoned 0xAA; capture-legal)
    hipMemsetAsync((char*)d_ws + (size_t)WS_RDY * 4, 0, NS * 4, stream);
    qws_kernel<<<GRID, 256, 0, stream>>>(x, hist, Wq, bq, Wk, ws);
    agg_kernel<<<NT, 64, 0, stream>>>(hist, Wv, bv, ws, out);
}